// Round 6
// baseline (29729.788 us; speedup 1.0000x reference)
//
#include <hip/hip_runtime.h>
#include <math.h>

#define T_LEN 4096
#define EDIM  256
#define HDIM  512
#define NTAGS 50
#define SENTW 0xFFFFFFFFu

__device__ __forceinline__ float sigm(float x) { return 1.0f / (1.0f + expf(-x)); }
__device__ __forceinline__ float u2f(unsigned u) { union { unsigned i; float f; } v; v.i = u; return v.f; }

// ---------------------------------------------------------------------------
// Persistent bidirectional LSTM scan (f32). R6: pure-FMA matvec + split-wait.
//   32 WGs x 512 threads (8 waves); blocks 0..15 forward, 16..31 backward.
//   WG g owns 32 hidden units [g*32,+32); wave wv owns 4 units
//   U = g*32 + wv*4 + j  =>  16 gate rows R(q,j) = q*512 + g*32 + wv*4 + j.
//   LANE owns columns: h cols [lane*8,+8), emb cols [lane*4,+4) => matvec is
//   128+64 pure v_fmac from register weights. No readlane broadcast.
// Sync (split-wait): hs[t] doubles as data+flag (memset 0xFF = -NaN,
// unproducible by o*tanh(c)). Wave wv polls ONLY its own 64-float segment
// [wv*64,+64) — 1 u64 per lane (lanes<32), relaxed agent loads — then writes
// it to LDS hl[512]; one __syncthreads; every lane reads its h8 = hl[lane*8..]
// (2x ds_read_b128). Poll traffic: 8x less than R5, 2x less than R4.
// Reduction: folding butterfly (verified R5). Round k (masks 1,2,4,8) folds
// acc-index bit against lane bit k; after 4 rounds lane l holds row
// r = 8*b0+4*b1+2*b2+b3 summed over lane bits 0..3; xor(16)+xor(32) complete
// the 64-lane sum. Gates of unit j_act=2*b2+b3 sit on consecutive lanes
// (base=l&60, offsets {0:i,1:g,2:f,3:o}); all lanes redundantly activate;
// lanes 0,4,8,12 of each wave store 4 contiguous dwords (one 16B chunk/wave).
// LDS reuse race-freedom: a wave passes its step-(s+1) poll only after ALL
// waves of this WG stored h_t, which happens after their step-s hl reads. QED.
// ---------------------------------------------------------------------------
__global__ __launch_bounds__(512, 1) void lstm_scan(
    const int* __restrict__ sent, const float* __restrict__ emb,
    const float* __restrict__ Wih_f, const float* __restrict__ Whh_f,
    const float* __restrict__ bih_f, const float* __restrict__ bhh_f,
    const float* __restrict__ Wih_b, const float* __restrict__ Whh_b,
    const float* __restrict__ bih_b, const float* __restrict__ bhh_b,
    float* hsf, float* hsb)
{
    const int tid  = threadIdx.x;
    const int lane = tid & 63;
    const int wv   = tid >> 6;          // 0..7
    const int dir  = blockIdx.x >> 4;
    const int g    = blockIdx.x & 15;

    const float* Wih = dir ? Wih_b : Wih_f;
    const float* Whh = dir ? Whh_b : Whh_f;
    const float* bih = dir ? bih_b : bih_f;
    const float* bhh = dir ? bhh_b : bhh_f;
    float* hs = dir ? hsb : hsf;

    // Register weights: wh[i][0..7] = Whh[R(i)][lane*8+m], wx[i][0..3].
    float wh[16][8], wx[16][4];
    #pragma unroll
    for (int i = 0; i < 16; ++i) {
        const int q = i >> 2, j = i & 3;
        const int R = q * 512 + g * 32 + wv * 4 + j;
        float4 a = *(const float4*)(Whh + (size_t)R * HDIM + lane * 8);
        float4 b = *(const float4*)(Whh + (size_t)R * HDIM + lane * 8 + 4);
        wh[i][0] = a.x; wh[i][1] = a.y; wh[i][2] = a.z; wh[i][3] = a.w;
        wh[i][4] = b.x; wh[i][5] = b.y; wh[i][6] = b.z; wh[i][7] = b.w;
        float4 c = *(const float4*)(Wih + (size_t)R * EDIM + lane * 4);
        wx[i][0] = c.x; wx[i][1] = c.y; wx[i][2] = c.z; wx[i][3] = c.w;
    }

    // Bias of the row this lane holds after the fold.
    const int b0 = lane & 1, b1 = (lane >> 1) & 1, b2 = (lane >> 2) & 1, b3 = (lane >> 3) & 1;
    const int r_fin = 8 * b0 + 4 * b1 + 2 * b2 + b3;
    const int R_fin = (r_fin >> 2) * 512 + g * 32 + wv * 4 + (r_fin & 3);
    const float bias_fin = bih[R_fin] + bhh[R_fin];

    const int j_act = 2 * b2 + b3;
    const int gbase = lane & 60;
    const bool is_store = ((lane & 3) == 0) && (lane < 16);
    const int u_glob = g * 32 + wv * 4 + j_act;

    __shared__ __align__(16) float hl[512];

    float c_state = 0.0f;

    // Embedding pipeline: lane holds emb[sent[t]][lane*4 + i].
    float4 ecur;
    {
        int t0 = dir ? (T_LEN - 1) : 0;
        ecur = *(const float4*)(emb + (size_t)sent[t0] * EDIM + lane * 4);
    }

    for (int s = 0; s < T_LEN; ++s) {
        const int t = dir ? (T_LEN - 1 - s) : s;

        // 1. Issue first poll sample ASAP (flies under prefetch + x-part).
        const unsigned long long* hp = nullptr;
        unsigned long long v = 0;
        if (s > 0 && lane < 32) {
            const int tp = dir ? (t + 1) : (t - 1);
            hp = (const unsigned long long*)(hs + (size_t)tp * HDIM) + wv * 32 + lane;
            v = __hip_atomic_load(hp, __ATOMIC_RELAXED, __HIP_MEMORY_SCOPE_AGENT);
        }

        // 2. Prefetch next step's embedding values (h-independent).
        float4 enext = make_float4(0.f, 0.f, 0.f, 0.f);
        if (s + 1 < T_LEN) {
            int tn = dir ? (t - 1) : (t + 1);
            enext = *(const float4*)(emb + (size_t)sent[tn] * EDIM + lane * 4);
        }

        // 3. x-part: 64 pure FMAs from registers (overlaps in-flight poll).
        float r[16];
        #pragma unroll
        for (int i = 0; i < 16; ++i) {
            r[i] = wx[i][0] * ecur.x;
            r[i] = fmaf(wx[i][1], ecur.y, r[i]);
            r[i] = fmaf(wx[i][2], ecur.z, r[i]);
            r[i] = fmaf(wx[i][3], ecur.w, r[i]);
        }

        // 4. Resolve poll for this wave's own 64-float segment; stage to LDS.
        if (s == 0) {
            if (lane < 32) {
                hl[wv * 64 + 2 * lane]     = 0.0f;
                hl[wv * 64 + 2 * lane + 1] = 0.0f;
            }
        } else if (lane < 32) {
            while (((unsigned)v == SENTW) || ((unsigned)(v >> 32) == SENTW))
                v = __hip_atomic_load(hp, __ATOMIC_RELAXED, __HIP_MEMORY_SCOPE_AGENT);
            hl[wv * 64 + 2 * lane]     = u2f((unsigned)v);
            hl[wv * 64 + 2 * lane + 1] = u2f((unsigned)(v >> 32));
        }
        __syncthreads();

        // 5. h-part: lane's own 8 columns from LDS, 128 pure FMAs.
        {
            float4 ha = *(const float4*)(hl + lane * 8);
            float4 hb = *(const float4*)(hl + lane * 8 + 4);
            float h8[8] = { ha.x, ha.y, ha.z, ha.w, hb.x, hb.y, hb.z, hb.w };
            #pragma unroll
            for (int i = 0; i < 16; ++i) {
                #pragma unroll
                for (int m = 0; m < 8; ++m)
                    r[i] = fmaf(wh[i][m], h8[m], r[i]);
            }
        }

        // 6. Folding butterfly reduction (16 rows x 64 lanes).
        #pragma unroll
        for (int k = 0; k < 4; ++k) {
            const int half = 8 >> k;
            const bool sel = (lane >> k) & 1;
            #pragma unroll
            for (int i = 0; i < half; ++i) {
                float mine  = sel ? r[i + half] : r[i];
                float other = sel ? r[i]        : r[i + half];
                r[i] = mine + __shfl_xor(other, 1 << k, 64);
            }
        }
        float tot = r[0];
        tot += __shfl_xor(tot, 16, 64);
        tot += __shfl_xor(tot, 32, 64);
        tot += bias_fin;

        // 7. Gather gates of unit j_act (consecutive lanes: i,g,f,o).
        float gi = __shfl(tot, gbase + 0, 64);
        float gg = __shfl(tot, gbase + 1, 64);
        float gf = __shfl(tot, gbase + 2, 64);
        float go = __shfl(tot, gbase + 3, 64);

        float iv = sigm(gi), fv = sigm(gf);
        float gv = tanhf(gg), ov = sigm(go);
        c_state = fv * c_state + iv * gv;
        float h = ov * tanhf(c_state);

        // 8. Publish: 4 lanes/wave store one contiguous 16B chunk per wave.
        if (is_store)
            __hip_atomic_store(hs + (size_t)t * HDIM + u_glob, h,
                               __ATOMIC_RELAXED, __HIP_MEMORY_SCOPE_AGENT);

        ecur = enext;
    }
}

// ---------------------------------------------------------------------------
// tag_space[t] = [hs_f[t] | hs_b[t]] @ W_out^T + b_out  (f32 out)
// ---------------------------------------------------------------------------
__global__ __launch_bounds__(256) void out_gemm(
    const float* __restrict__ hsf, const float* __restrict__ hsb,
    const float* __restrict__ Wout, const float* __restrict__ bout,
    float* __restrict__ out)
{
    const int t   = blockIdx.x;
    const int tid = threadIdx.x;
    __shared__ float h2[1024];

    if (tid < 128)
        *(float4*)(h2 + tid * 4) = *(const float4*)(hsf + (size_t)t * HDIM + tid * 4);
    else
        *(float4*)(h2 + 512 + (tid - 128) * 4) = *(const float4*)(hsb + (size_t)t * HDIM + (tid - 128) * 4);
    __syncthreads();

    const int wv = tid >> 6, lane = tid & 63;
    for (int tag = wv; tag < NTAGS; tag += 4) {
        const float4* wr = (const float4*)(Wout + (size_t)tag * (2 * HDIM));
        float p = 0.0f;
        #pragma unroll
        for (int c = lane; c < 256; c += 64) {
            float4 wv4 = wr[c];
            float4 hv  = *(const float4*)(h2 + c * 4);
            p += wv4.x * hv.x + wv4.y * hv.y + wv4.z * hv.z + wv4.w * hv.w;
        }
        p += __shfl_down(p, 32, 64);
        p += __shfl_down(p, 16, 64);
        p += __shfl_down(p, 8, 64);
        p += __shfl_down(p, 4, 64);
        p += __shfl_down(p, 2, 64);
        p += __shfl_down(p, 1, 64);
        if (lane == 0) out[(size_t)t * NTAGS + tag] = p + bout[tag];
    }
}

// ---------------------------------------------------------------------------
extern "C" void kernel_launch(void* const* d_in, const int* in_sizes, int n_in,
                              void* d_out, int out_size, void* d_ws, size_t ws_size,
                              hipStream_t stream)
{
    const int*   sent  = (const int*)d_in[0];
    const float* emb   = (const float*)d_in[1];
    const float* Wih_f = (const float*)d_in[2];
    const float* Whh_f = (const float*)d_in[3];
    const float* bih_f = (const float*)d_in[4];
    const float* bhh_f = (const float*)d_in[5];
    const float* Wih_b = (const float*)d_in[6];
    const float* Whh_b = (const float*)d_in[7];
    const float* bih_b = (const float*)d_in[8];
    const float* bhh_b = (const float*)d_in[9];
    const float* Wout  = (const float*)d_in[10];
    const float* bout  = (const float*)d_in[11];
    float* out = (float*)d_out;

    char* ws = (char*)d_ws;
    // Workspace: hsf [4096*512 f32] @ 0 (8 MiB), hsb @ 8 MiB. Both double as
    // sync flags: sentinel-fill with 0xFF (-NaN, never produced by o*tanh(c)).
    float* hsf = (float*)(ws);
    float* hsb = (float*)(ws + 8388608);
    hipMemsetAsync(ws, 0xFF, 16777216, stream);

    lstm_scan<<<32, 512, 0, stream>>>(sent, emb,
                                      Wih_f, Whh_f, bih_f, bhh_f,
                                      Wih_b, Whh_b, bih_b, bhh_b,
                                      hsf, hsb);
    out_gemm<<<T_LEN, 256, 0, stream>>>(hsf, hsb, Wout, bout, out);
}

// Round 7
// 9943.179 us; speedup vs baseline: 2.9900x; 2.9900x over previous
//
#include <hip/hip_runtime.h>
#include <math.h>

#define T_LEN 4096
#define EDIM  256
#define HDIM  512
#define NTAGS 50
#define SENTW 0xFFFFFFFFu

__device__ __forceinline__ float sigm(float x) { return 1.0f / (1.0f + expf(-x)); }
__device__ __forceinline__ float u2f(unsigned u) { union { unsigned i; float f; } v; v.i = u; return v.f; }

// ---------------------------------------------------------------------------
// Persistent bidirectional LSTM scan (f32). R7 = R4's proven sync skeleton
// (2.18 us/step) + cheapened compute path.
//   64 WGs x 256 threads (4 waves); blocks 0..31 fwd, 32..63 bwd.
//   WG g owns units [g*16,+16) => 64 gate rows (row = q*16+u local).
//   Wave wv owns column quarter [wv*128,+128) of W_hh and [wv*64,+64) of Wih.
//   LANE = row: lane l holds W_hh[R(l)][quarter] (128 VGPR) + Wih[R(l)][..]
//   (64 VGPR), R(l) = (l>>4)*512 + g*16 + (l&15).
// Sync (R4-identical): hs[t] doubles as data+flag (memset 0xFF = -NaN,
// unproducible by o*tanh(c)). Wave wv polls ONLY its own quarter: 1 u64/lane,
// relaxed agent loads, pipelined double-poll (two samples in flight).
// h broadcast: lane ds_writes its 2 polled floats into a WAVE-PRIVATE LDS
// strip, then 32x ds_read_b128 same-address broadcast (conflict-free, no
// barrier: same-wave RAW is ordered by lgkmcnt). 128 pure v_fmac. Same trick
// for x (16 reads + 64 fmac), overlapped with in-flight polls.
// Combine: pl[parity][wv*65 + row] = partial; ONE __syncthreads; finalize
// DISTRIBUTED: wave wv handles units wv*4..+3. Lane l: u_rel=l>>4,
// qg=(l>>2)&3, qq=l&3 reads pl[parity][qq*65 + qg*16 + wv*4+u_rel], 2x
// shfl_xor over qq, +bias, gate-gather via shfl from base=l&48 (+0:i,+4:f,
// +8:g,+12:o), redundant activation per 16-lane unit-group, lanes l&15==0
// store (4 dwords/wave, one 16B chunk; WG total 64B line).
// pl parity race-freedom (R4-proven): rewrite of pl[s&1] at s+2 requires
// passing barrier(s+1), which requires all readers arrived there. QED.
// ---------------------------------------------------------------------------
__global__ __launch_bounds__(256, 1) void lstm_scan(
    const int* __restrict__ sent, const float* __restrict__ emb,
    const float* __restrict__ Wih_f, const float* __restrict__ Whh_f,
    const float* __restrict__ bih_f, const float* __restrict__ bhh_f,
    const float* __restrict__ Wih_b, const float* __restrict__ Whh_b,
    const float* __restrict__ bih_b, const float* __restrict__ bhh_b,
    float* hsf, float* hsb)
{
    const int tid  = threadIdx.x;
    const int lane = tid & 63;
    const int wv   = tid >> 6;          // 0..3 = column quarter
    const int dir  = blockIdx.x >> 5;
    const int g    = blockIdx.x & 31;

    const float* Wih = dir ? Wih_b : Wih_f;
    const float* Whh = dir ? Whh_b : Whh_f;
    const float* bih = dir ? bih_b : bih_f;
    const float* bhh = dir ? bhh_b : bhh_f;
    float* hs = dir ? hsb : hsf;

    // Lane = row. R = q*512 + g*16 + u, q = lane>>4, u = lane&15.
    const int R = (lane >> 4) * 512 + g * 16 + (lane & 15);

    // W_hh[R][wv*128 .. +128) -> 128 VGPRs; Wih[R][wv*64 .. +64) -> 64 VGPRs.
    float wh[128];
    {
        const float* base = Whh + (size_t)R * HDIM + wv * 128;
        #pragma unroll
        for (int i = 0; i < 32; ++i) {
            float4 v = *(const float4*)(base + 4 * i);
            wh[4*i] = v.x; wh[4*i+1] = v.y; wh[4*i+2] = v.z; wh[4*i+3] = v.w;
        }
    }
    float wx[64];
    {
        const float* base = Wih + (size_t)R * EDIM + wv * 64;
        #pragma unroll
        for (int i = 0; i < 16; ++i) {
            float4 v = *(const float4*)(base + 4 * i);
            wx[4*i] = v.x; wx[4*i+1] = v.y; wx[4*i+2] = v.z; wx[4*i+3] = v.w;
        }
    }

    // Finalize constants for lane l.
    const int u_rel = lane >> 4;            // unit handled by this lane's group
    const int qg    = (lane >> 2) & 3;      // gate of the pl value this lane reads
    const int qq    = lane & 3;             // quarter of the pl value
    const int u_own = wv * 4 + u_rel;       // local unit (0..15) of this wave
    const int R_fin = qg * 512 + g * 16 + u_own;
    const float bias_fin = bih[R_fin] + bhh[R_fin];
    const int gbase = lane & 48;
    const bool is_store = ((lane & 15) == 0);
    const int u_glob = g * 16 + u_own;

    __shared__ __align__(16) float hl[512];      // wave-private strips [wv*128,+128)
    __shared__ __align__(16) float xl[256];      // wave-private strips [wv*64,+64)
    __shared__ float pl[2][260];                 // stride-65 quarters

    float c_state = 0.0f;

    // Embedding pipeline: lane holds emb[sent[t]][wv*64 + lane&63... 1 float].
    float ecur;
    {
        int t0 = dir ? (T_LEN - 1) : 0;
        ecur = emb[(size_t)sent[t0] * EDIM + wv * 64 + (lane & 63)];
    }

    for (int s = 0; s < T_LEN; ++s) {
        const int t = dir ? (T_LEN - 1 - s) : s;

        // 1. Issue pipelined double-poll FIRST (before emb prefetch, so the
        //    first check's vmcnt wait does not drain the HBM emb miss).
        const unsigned long long* hp = nullptr;
        unsigned long long v0 = 0, v1 = 0;
        if (s > 0) {
            const int tp = dir ? (t + 1) : (t - 1);
            hp = (const unsigned long long*)(hs + (size_t)tp * HDIM) + wv * 64 + lane;
            v0 = __hip_atomic_load(hp, __ATOMIC_RELAXED, __HIP_MEMORY_SCOPE_AGENT);
            v1 = __hip_atomic_load(hp, __ATOMIC_RELAXED, __HIP_MEMORY_SCOPE_AGENT);
        }

        // 2. Prefetch next step's embedding value (h-independent).
        float enext = 0.0f;
        if (s + 1 < T_LEN) {
            int tn = dir ? (t - 1) : (t + 1);
            enext = emb[(size_t)sent[tn] * EDIM + wv * 64 + lane];
        }

        // 3. x-part: stage ecur into wave-private LDS strip, broadcast-read,
        //    64 pure FMAs. Overlaps the in-flight poll loads.
        xl[wv * 64 + lane] = ecur;
        float r;
        {
            float4 x4 = *(const float4*)(xl + wv * 64);
            r = wx[0] * x4.x;
            r = fmaf(wx[1], x4.y, r);
            r = fmaf(wx[2], x4.z, r);
            r = fmaf(wx[3], x4.w, r);
            #pragma unroll
            for (int c = 1; c < 16; ++c) {
                float4 xv = *(const float4*)(xl + wv * 64 + 4 * c);
                r = fmaf(wx[4*c+0], xv.x, r);
                r = fmaf(wx[4*c+1], xv.y, r);
                r = fmaf(wx[4*c+2], xv.z, r);
                r = fmaf(wx[4*c+3], xv.w, r);
            }
        }

        // 4. Resolve poll (own quarter only); stage h to wave-private strip.
        if (s == 0) {
            hl[wv * 128 + 2 * lane]     = 0.0f;
            hl[wv * 128 + 2 * lane + 1] = 0.0f;
        } else {
            while (((unsigned)v0 == SENTW) || ((unsigned)(v0 >> 32) == SENTW)) {
                v0 = v1;
                v1 = __hip_atomic_load(hp, __ATOMIC_RELAXED, __HIP_MEMORY_SCOPE_AGENT);
            }
            hl[wv * 128 + 2 * lane]     = u2f((unsigned)v0);
            hl[wv * 128 + 2 * lane + 1] = u2f((unsigned)(v0 >> 32));
        }
        // Same-wave ds_write -> ds_read: ordered by lgkmcnt, no barrier.

        // 5. h-part: 32 broadcast ds_read_b128 + 128 pure FMAs.
        if (s > 0) {
            #pragma unroll
            for (int c = 0; c < 32; ++c) {
                float4 hv = *(const float4*)(hl + wv * 128 + 4 * c);
                r = fmaf(wh[4*c+0], hv.x, r);
                r = fmaf(wh[4*c+1], hv.y, r);
                r = fmaf(wh[4*c+2], hv.z, r);
                r = fmaf(wh[4*c+3], hv.w, r);
            }
        }

        // 6. Publish partial, one barrier.
        pl[s & 1][wv * 65 + lane] = r;
        __syncthreads();

        // 7. Distributed finalize: this wave's 4 units.
        {
            const float* pb = pl[s & 1];
            float vsum = pb[qq * 65 + qg * 16 + u_own];
            vsum += __shfl_xor(vsum, 1, 64);
            vsum += __shfl_xor(vsum, 2, 64);
            vsum += bias_fin;
            float gi = __shfl(vsum, gbase + 0,  64);
            float gf = __shfl(vsum, gbase + 4,  64);
            float gg = __shfl(vsum, gbase + 8,  64);
            float go = __shfl(vsum, gbase + 12, 64);

            float iv = sigm(gi), fv = sigm(gf);
            float gv = tanhf(gg), ov = sigm(go);
            c_state = fv * c_state + iv * gv;
            float h = ov * tanhf(c_state);

            if (is_store)
                __hip_atomic_store(hs + (size_t)t * HDIM + u_glob, h,
                                   __ATOMIC_RELAXED, __HIP_MEMORY_SCOPE_AGENT);
        }
        ecur = enext;
    }
}

// ---------------------------------------------------------------------------
// tag_space[t] = [hs_f[t] | hs_b[t]] @ W_out^T + b_out  (f32 out)
// ---------------------------------------------------------------------------
__global__ __launch_bounds__(256) void out_gemm(
    const float* __restrict__ hsf, const float* __restrict__ hsb,
    const float* __restrict__ Wout, const float* __restrict__ bout,
    float* __restrict__ out)
{
    const int t   = blockIdx.x;
    const int tid = threadIdx.x;
    __shared__ float h2[1024];

    if (tid < 128)
        *(float4*)(h2 + tid * 4) = *(const float4*)(hsf + (size_t)t * HDIM + tid * 4);
    else
        *(float4*)(h2 + 512 + (tid - 128) * 4) = *(const float4*)(hsb + (size_t)t * HDIM + (tid - 128) * 4);
    __syncthreads();

    const int wv = tid >> 6, lane = tid & 63;
    for (int tag = wv; tag < NTAGS; tag += 4) {
        const float4* wr = (const float4*)(Wout + (size_t)tag * (2 * HDIM));
        float p = 0.0f;
        #pragma unroll
        for (int c = lane; c < 256; c += 64) {
            float4 wv4 = wr[c];
            float4 hv  = *(const float4*)(h2 + c * 4);
            p += wv4.x * hv.x + wv4.y * hv.y + wv4.z * hv.z + wv4.w * hv.w;
        }
        p += __shfl_down(p, 32, 64);
        p += __shfl_down(p, 16, 64);
        p += __shfl_down(p, 8, 64);
        p += __shfl_down(p, 4, 64);
        p += __shfl_down(p, 2, 64);
        p += __shfl_down(p, 1, 64);
        if (lane == 0) out[(size_t)t * NTAGS + tag] = p + bout[tag];
    }
}

// ---------------------------------------------------------------------------
extern "C" void kernel_launch(void* const* d_in, const int* in_sizes, int n_in,
                              void* d_out, int out_size, void* d_ws, size_t ws_size,
                              hipStream_t stream)
{
    const int*   sent  = (const int*)d_in[0];
    const float* emb   = (const float*)d_in[1];
    const float* Wih_f = (const float*)d_in[2];
    const float* Whh_f = (const float*)d_in[3];
    const float* bih_f = (const float*)d_in[4];
    const float* bhh_f = (const float*)d_in[5];
    const float* Wih_b = (const float*)d_in[6];
    const float* Whh_b = (const float*)d_in[7];
    const float* bih_b = (const float*)d_in[8];
    const float* bhh_b = (const float*)d_in[9];
    const float* Wout  = (const float*)d_in[10];
    const float* bout  = (const float*)d_in[11];
    float* out = (float*)d_out;

    char* ws = (char*)d_ws;
    // Workspace: hsf [4096*512 f32] @ 0 (8 MiB), hsb @ 8 MiB. Both double as
    // sync flags: sentinel-fill with 0xFF (-NaN, never produced by o*tanh(c)).
    float* hsf = (float*)(ws);
    float* hsb = (float*)(ws + 8388608);
    hipMemsetAsync(ws, 0xFF, 16777216, stream);

    lstm_scan<<<64, 256, 0, stream>>>(sent, emb,
                                      Wih_f, Whh_f, bih_f, bhh_f,
                                      Wih_b, Whh_b, bih_b, bhh_b,
                                      hsf, hsb);
    out_gemm<<<T_LEN, 256, 0, stream>>>(hsf, hsb, Wout, bout, out);
}